// Round 14
// baseline (246.813 us; speedup 1.0000x reference)
//
#include <hip/hip_runtime.h>
#include <math.h>

#define NN 100000
#define NE 1600000
#define EE 1700000       // NE + NN self loops
#define HD 128
#define NH (NN*HD)

#define BSH 8            // bucket = dst >> 8  (256 nodes per bucket)
#define NBUK 391         // ceil(NN / 256)
#define CAP 6144         // per-bucket staging capacity (mean 4352, sigma ~66)
#define EPB 4096         // edges per partition block
#define P1B ((EE + EPB - 1) / EPB)   // 416
#define GEMMB 1563       // gemm blocks (64 rows each)
#define AGGB 1563        // gat blocks (64 nodes each, 4 per 16-lane group)

typedef _Float16 f16x8 __attribute__((ext_vector_type(8)));
typedef float    f32x4 __attribute__((ext_vector_type(4)));

__device__ __forceinline__ float fast_tanh(float x) {
    float e = __expf(2.f * x);
    return 1.f - 2.f * __builtin_amdgcn_rcpf(e + 1.f);
}

// ====== prep: W (fp32 [k][n]) -> Wt (fp16 [n][k]) for both layers + zero bucketCount ======
__global__ void prep_kernel(const float* __restrict__ W1, const float* __restrict__ W2,
                            _Float16* __restrict__ Wt1, _Float16* __restrict__ Wt2,
                            int* __restrict__ bucketCount) {
    int b = blockIdx.x;
    int t = threadIdx.x;
    if (b < 128) {
        const float* W = (b < 64) ? W1 : W2;
        _Float16* Wt   = (b < 64) ? Wt1 : Wt2;
        int e = (b & 63) * 256 + t;
        int k = e >> 7, n = e & 127;
        Wt[n*HD + k] = (_Float16)W[e];
    } else {
        for (int i = t; i < NBUK; i += 256) bucketCount[i] = 0;
    }
}

// ================= CSR phase 1: bucket partition (standalone, early) =================
__launch_bounds__(256) __global__
void partition_kernel(const int* __restrict__ ei, int* __restrict__ bucketCount,
                      unsigned* __restrict__ stage) {
    __shared__ int hist[NBUK];
    __shared__ int base[NBUK];
    int t = threadIdx.x;
    for (int i = t; i < NBUK; i += 256) hist[i] = 0;
    __syncthreads();
    int e0 = blockIdx.x * EPB;
    int e1 = min(e0 + EPB, EE);
    for (int e = e0 + t; e < e1; e += 256) {
        int d = (e < NE) ? ei[NE + e] : e - NE;
        atomicAdd(&hist[d >> BSH], 1);
    }
    __syncthreads();
    for (int i = t; i < NBUK; i += 256) {
        base[i] = atomicAdd(&bucketCount[i], hist[i]);
        hist[i] = 0;                       // reuse as cursor
    }
    __syncthreads();
    for (int e = e0 + t; e < e1; e += 256) {
        int s, d;
        if (e < NE) { s = ei[e]; d = ei[NE + e]; } else { s = e - NE; d = s; }
        int b = d >> BSH;
        int pos = base[b] + atomicAdd(&hist[b], 1);
        if (pos < CAP)
            stage[(size_t)b * CAP + pos] = (unsigned)s | ((unsigned)(d & 255) << 20);
    }
}

// ====== FUSED: layer-1 GEMM(+scores)  ∥  CSR bucket_build (independent work) ======
__launch_bounds__(256) __global__
void gemm_bb_kernel(const float* __restrict__ A, const _Float16* __restrict__ Wt,
                    _Float16* __restrict__ H, const float* __restrict__ a_src,
                    const float* __restrict__ a_dst, float* __restrict__ s_src,
                    float* __restrict__ s_dst,
                    const unsigned* __restrict__ stage, const int* __restrict__ bucketCount,
                    int* __restrict__ row_ptr, int* __restrict__ csr_src) {
    __shared__ __align__(16) char smem[HD*HD*2 + HD*8];    // 33 KB union
    int bid = blockIdx.x;
    int t = threadIdx.x;

    if (bid < GEMMB) {
        // ---------------- GEMM body ----------------
        _Float16* Wl = (_Float16*)smem;                    // 32 KB, slot-swizzled
        float* asl = (float*)(smem + HD*HD*2);
        float* adl = asl + HD;
        #pragma unroll
        for (int i = 0; i < 8; ++i) {
            int f = t + 256*i;                 // float4 index over 2048
            int n = f >> 4, slot = f & 15;
            int phys = n*16 + (slot ^ (n & 7));
            *(float4*)(Wl + (size_t)phys*8) = ((const float4*)Wt)[f];
        }
        if (t < HD) { asl[t] = a_src[t]; adl[t] = a_dst[t]; }
        __syncthreads();

        int wave = t >> 6, lane = t & 63;
        int row0 = bid*64 + wave*16;
        int h8   = lane >> 4;
        int col  = lane & 15;
        int arow = row0 + col; if (arow >= NN) arow = NN - 1;
        const float* Af = A + (size_t)arow*HD + h8*8;

        f32x4 acc[8];
        #pragma unroll
        for (int i = 0; i < 8; ++i) acc[i] = (f32x4){0.f,0.f,0.f,0.f};

        #pragma unroll
        for (int step = 0; step < 4; ++step) {
            float4 fa = *(const float4*)(Af + step*32);
            float4 fb = *(const float4*)(Af + step*32 + 4);
            f16x8 a = { (_Float16)fa.x, (_Float16)fa.y, (_Float16)fa.z, (_Float16)fa.w,
                        (_Float16)fb.x, (_Float16)fb.y, (_Float16)fb.z, (_Float16)fb.w };
            #pragma unroll
            for (int nt = 0; nt < 8; ++nt) {
                int n = nt*16 + col;
                int slot = step*4 + h8;
                f16x8 bfr = *(const f16x8*)(Wl + (size_t)(n*16 + (slot ^ (n & 7)))*8);
                acc[nt] = __builtin_amdgcn_mfma_f32_16x16x32_f16(a, bfr, acc[nt], 0, 0, 0);
            }
        }

        int orow0 = row0 + h8*4;               // D: col=lane&15, row=(lane>>4)*4+reg
        #pragma unroll
        for (int nt = 0; nt < 8; ++nt) {
            int c = nt*16 + col;
            #pragma unroll
            for (int r = 0; r < 4; ++r) {
                int row = orow0 + r;
                if (row < NN) H[(size_t)row*HD + c] = (_Float16)acc[nt][r];
            }
        }

        float pS[4] = {0.f,0.f,0.f,0.f}, pD[4] = {0.f,0.f,0.f,0.f};
        #pragma unroll
        for (int nt = 0; nt < 8; ++nt) {
            float as_ = asl[nt*16 + col], ad_ = adl[nt*16 + col];
            #pragma unroll
            for (int r = 0; r < 4; ++r) { pS[r] += acc[nt][r]*as_; pD[r] += acc[nt][r]*ad_; }
        }
        #pragma unroll
        for (int off = 1; off < 16; off <<= 1) {
            #pragma unroll
            for (int r = 0; r < 4; ++r) {
                pS[r] += __shfl_xor(pS[r], off);
                pD[r] += __shfl_xor(pD[r], off);
            }
        }
        if (col == 0) {
            #pragma unroll
            for (int r = 0; r < 4; ++r) {
                int row = orow0 + r;
                if (row < NN) { s_src[row] = pS[r]; s_dst[row] = pD[r]; }
            }
        }
    } else {
        // ---------------- bucket_build body ----------------
        int b = bid - GEMMB;
        int* ldeg = (int*)smem;                // 256 ints
        int* loff = ldeg + 256;                // 256 ints
        int* sbase = loff + 256;               // 1 int
        int c = 0;
        if (t < b) c = bucketCount[t];
        if (t + 256 < b) c += bucketCount[t + 256];
        loff[t] = c;
        ldeg[t] = 0;
        __syncthreads();
        for (int off = 128; off >= 1; off >>= 1) {
            if (t < off) loff[t] += loff[t + off];
            __syncthreads();
        }
        if (t == 0) sbase[0] = loff[0];
        __syncthreads();
        int cnt  = bucketCount[b];
        int base = sbase[0];
        const unsigned* sp = stage + (size_t)b * CAP;
        for (int i = t; i < cnt; i += 256) atomicAdd(&ldeg[sp[i] >> 20], 1);
        __syncthreads();
        int v = ldeg[t];
        loff[t] = v;
        __syncthreads();
        for (int off = 1; off < 256; off <<= 1) {
            int tmp = (t >= off) ? loff[t - off] : 0;
            __syncthreads();
            loff[t] += tmp;
            __syncthreads();
        }
        int excl = loff[t] - v;
        int n = (b << BSH) + t;
        if (n < NN) row_ptr[n] = base + excl;
        if (b == NBUK - 1 && t == 0) row_ptr[NN] = EE;
        ldeg[t] = excl;                        // reuse as cursor
        __syncthreads();
        for (int i = t; i < cnt; i += 256) {
            unsigned p = sp[i];
            int lp = atomicAdd(&ldeg[p >> 20], 1);
            csr_src[base + lp] = (int)(p & 0xFFFFFu);
        }
    }
}

// ================= layer-2 GEMM(+scores), no fused tail =================
__launch_bounds__(256) __global__
void gemm_kernel(const float* __restrict__ A, const _Float16* __restrict__ Wt,
                 _Float16* __restrict__ H, const float* __restrict__ a_src,
                 const float* __restrict__ a_dst, float* __restrict__ s_src,
                 float* __restrict__ s_dst) {
    __shared__ __align__(16) char smem[HD*HD*2 + HD*8];
    int bid = blockIdx.x;
    int t = threadIdx.x;
    _Float16* Wl = (_Float16*)smem;
    float* asl = (float*)(smem + HD*HD*2);
    float* adl = asl + HD;
    #pragma unroll
    for (int i = 0; i < 8; ++i) {
        int f = t + 256*i;
        int n = f >> 4, slot = f & 15;
        int phys = n*16 + (slot ^ (n & 7));
        *(float4*)(Wl + (size_t)phys*8) = ((const float4*)Wt)[f];
    }
    if (t < HD) { asl[t] = a_src[t]; adl[t] = a_dst[t]; }
    __syncthreads();

    int wave = t >> 6, lane = t & 63;
    int row0 = bid*64 + wave*16;
    int h8   = lane >> 4;
    int col  = lane & 15;
    int arow = row0 + col; if (arow >= NN) arow = NN - 1;
    const float* Af = A + (size_t)arow*HD + h8*8;

    f32x4 acc[8];
    #pragma unroll
    for (int i = 0; i < 8; ++i) acc[i] = (f32x4){0.f,0.f,0.f,0.f};

    #pragma unroll
    for (int step = 0; step < 4; ++step) {
        float4 fa = *(const float4*)(Af + step*32);
        float4 fb = *(const float4*)(Af + step*32 + 4);
        f16x8 a = { (_Float16)fa.x, (_Float16)fa.y, (_Float16)fa.z, (_Float16)fa.w,
                    (_Float16)fb.x, (_Float16)fb.y, (_Float16)fb.z, (_Float16)fb.w };
        #pragma unroll
        for (int nt = 0; nt < 8; ++nt) {
            int n = nt*16 + col;
            int slot = step*4 + h8;
            f16x8 bfr = *(const f16x8*)(Wl + (size_t)(n*16 + (slot ^ (n & 7)))*8);
            acc[nt] = __builtin_amdgcn_mfma_f32_16x16x32_f16(a, bfr, acc[nt], 0, 0, 0);
        }
    }

    int orow0 = row0 + h8*4;
    #pragma unroll
    for (int nt = 0; nt < 8; ++nt) {
        int c = nt*16 + col;
        #pragma unroll
        for (int r = 0; r < 4; ++r) {
            int row = orow0 + r;
            if (row < NN) H[(size_t)row*HD + c] = (_Float16)acc[nt][r];
        }
    }

    float pS[4] = {0.f,0.f,0.f,0.f}, pD[4] = {0.f,0.f,0.f,0.f};
    #pragma unroll
    for (int nt = 0; nt < 8; ++nt) {
        float as_ = asl[nt*16 + col], ad_ = adl[nt*16 + col];
        #pragma unroll
        for (int r = 0; r < 4; ++r) { pS[r] += acc[nt][r]*as_; pD[r] += acc[nt][r]*ad_; }
    }
    #pragma unroll
    for (int off = 1; off < 16; off <<= 1) {
        #pragma unroll
        for (int r = 0; r < 4; ++r) {
            pS[r] += __shfl_xor(pS[r], off);
            pD[r] += __shfl_xor(pD[r], off);
        }
    }
    if (col == 0) {
        #pragma unroll
        for (int r = 0; r < 4; ++r) {
            int row = orow0 + r;
            if (row < NN) { s_src[row] = pS[r]; s_dst[row] = pD[r]; }
        }
    }
}

// ================= fused per-node softmax + gather-aggregate =================
// Block owns 64 nodes; each 16-lane group walks 4 nodes as ONE flattened stream
// (node = blk*64 + gid + k*16, k=0..3). Wave cost = max over groups of SUM of 4
// degrees (1.12x inflation) instead of max of single degrees (1.22x).
template<int LAYER>
__launch_bounds__(256) __global__
void gat_node_kernel(const int* __restrict__ row_ptr, const int* __restrict__ csr_src,
                     const float* __restrict__ s_src, const float* __restrict__ s_dst,
                     const _Float16* __restrict__ Hh, const float* __restrict__ bias,
                     float* __restrict__ out) {
    int t = threadIdx.x;
    int gid = t >> 4;                       // group in block: 0..15
    int l16 = t & 15;
    int base = blockIdx.x * 64 + gid;
    float4 b0 = *(const float4*)(bias + l16*8);
    float4 b1 = *(const float4*)(bias + l16*8 + 4);

    int k = 0;
    int n = base;
    bool active = n < NN;
    int r1 = 0, last = 0, j = 0;
    float sdv = 0.f, denom = 0.f;
    float acc[8] = {0.f,0.f,0.f,0.f,0.f,0.f,0.f,0.f};
    if (active) {
        j = row_ptr[n]; r1 = row_ptr[n+1]; last = r1 - 1; sdv = s_dst[n];
    }

    while (__any(active)) {
        if (active) {
            int jB = j+1 <= last ? j+1 : last;
            int jC = j+2 <= last ? j+2 : last;
            int jD = j+3 <= last ? j+3 : last;
            int sA = csr_src[j];
            int sB = csr_src[jB];
            int sC = csr_src[jC];
            int sD = csr_src[jD];
            // issue all 8 gathers before dependent compute
            f16x8 hA = *(const f16x8*)(Hh + (unsigned)(sA << 7) + l16*8);
            f16x8 hB = *(const f16x8*)(Hh + (unsigned)(sB << 7) + l16*8);
            f16x8 hC = *(const f16x8*)(Hh + (unsigned)(sC << 7) + l16*8);
            f16x8 hD = *(const f16x8*)(Hh + (unsigned)(sD << 7) + l16*8);
            float eA = s_src[sA] + sdv;
            float eB = s_src[sB] + sdv;
            float eC = s_src[sC] + sdv;
            float eD = s_src[sD] + sdv;
            eA = eA > 0.f ? eA : 0.2f*eA;  eB = eB > 0.f ? eB : 0.2f*eB;
            eC = eC > 0.f ? eC : 0.2f*eC;  eD = eD > 0.f ? eD : 0.2f*eD;
            float wA = __expf(fminf(eA, 80.f));
            float wB = (j+1 < r1) ? __expf(fminf(eB, 80.f)) : 0.f;
            float wC = (j+2 < r1) ? __expf(fminf(eC, 80.f)) : 0.f;
            float wD = (j+3 < r1) ? __expf(fminf(eD, 80.f)) : 0.f;
            denom += (wA + wB) + (wC + wD);
            #pragma unroll
            for (int i = 0; i < 8; ++i)
                acc[i] += wA*(float)hA[i] + wB*(float)hB[i] + wC*(float)hC[i] + wD*(float)hD[i];
            j += 4;
            if (j >= r1) {
                // finalize node n
                float inv = __builtin_amdgcn_rcpf(denom);
                float* op = out + (unsigned)(n << 7) + l16*8;
                float r[8];
                r[0]=acc[0]*inv+b0.x; r[1]=acc[1]*inv+b0.y; r[2]=acc[2]*inv+b0.z; r[3]=acc[3]*inv+b0.w;
                r[4]=acc[4]*inv+b1.x; r[5]=acc[5]*inv+b1.y; r[6]=acc[6]*inv+b1.z; r[7]=acc[7]*inv+b1.w;
                if (LAYER == 1) {
                    #pragma unroll
                    for (int i = 0; i < 8; ++i) r[i] = fast_tanh(r[i]);
                } else {
                    float4 x0 = *(const float4*)op;
                    float4 x1 = *(const float4*)(op + 4);
                    r[0]=fmaxf(x0.x,r[0]); r[1]=fmaxf(x0.y,r[1]); r[2]=fmaxf(x0.z,r[2]); r[3]=fmaxf(x0.w,r[3]);
                    r[4]=fmaxf(x1.x,r[4]); r[5]=fmaxf(x1.y,r[5]); r[6]=fmaxf(x1.z,r[6]); r[7]=fmaxf(x1.w,r[7]);
                }
                *(float4*)op       = make_float4(r[0],r[1],r[2],r[3]);
                *(float4*)(op + 4) = make_float4(r[4],r[5],r[6],r[7]);
                // advance to next node of this group
                ++k;
                n = base + k*16;
                active = (k < 4) && (n < NN);
                if (active) {
                    j = row_ptr[n]; r1 = row_ptr[n+1]; last = r1 - 1; sdv = s_dst[n];
                    denom = 0.f;
                    #pragma unroll
                    for (int i = 0; i < 8; ++i) acc[i] = 0.f;
                }
            }
        }
    }
}

extern "C" void kernel_launch(void* const* d_in, const int* in_sizes, int n_in,
                              void* d_out, int out_size, void* d_ws, size_t ws_size,
                              hipStream_t stream) {
    const float* x   = (const float*)d_in[0];
    const int*   ei  = (const int*)d_in[1];
    // d_in[2] = edge_weight, unused by GATConv(edge_dim=None)
    const float* W1  = (const float*)d_in[3];
    const float* as1 = (const float*)d_in[4];
    const float* ad1 = (const float*)d_in[5];
    const float* b1  = (const float*)d_in[6];
    const float* W2  = (const float*)d_in[7];
    const float* as2 = (const float*)d_in[8];
    const float* ad2 = (const float*)d_in[9];
    const float* b2  = (const float*)d_in[10];
    float* out = (float*)d_out;

    char* wsb = (char*)d_ws;
    _Float16* h   = (_Float16*)wsb;                  // NH halves (25.6 MB)
    _Float16* Wt1 = h + NH;                          // 16384 halves
    _Float16* Wt2 = Wt1 + HD*HD;                     // 16384 halves
    float* ssrc   = (float*)(Wt2 + HD*HD);           // NN
    float* sdst   = ssrc + NN;                       // NN
    int* row_ptr  = (int*)(sdst + NN);               // NN+2
    int* csr_src  = row_ptr + NN + 2;                // EE
    int* bucketCount = csr_src + EE;                 // NBUK (zeroed by prep each launch)
    unsigned* stage  = (unsigned*)(bucketCount + NBUK + 1);  // NBUK*CAP (9.6 MB)

    dim3 B(256);

    // ===== prep: Wt transposes (both layers) + zero bucket counters =====
    prep_kernel<<<129, B, 0, stream>>>(W1, W2, Wt1, Wt2, bucketCount);

    // ===== CSR phase 1 (early, standalone; only needs ei) =====
    partition_kernel<<<P1B, B, 0, stream>>>(ei, bucketCount, stage);

    // ===== layer-1 GEMM ∥ CSR bucket_build (independent work, one dispatch) =====
    gemm_bb_kernel<<<GEMMB + NBUK, B, 0, stream>>>(x, Wt1, h, as1, ad1, ssrc, sdst,
                                                   stage, bucketCount, row_ptr, csr_src);

    // ===== layer 1 aggregate =====
    gat_node_kernel<1><<<AGGB, B, 0, stream>>>(row_ptr, csr_src, ssrc, sdst, h, b1, out);

    // ===== layer 2 (x1 fp32 lives in d_out; max fused into epilogue) =====
    gemm_kernel<<<GEMMB, B, 0, stream>>>(out, Wt2, h, as2, ad2, ssrc, sdst);
    gat_node_kernel<2><<<AGGB, B, 0, stream>>>(row_ptr, csr_src, ssrc, sdst, h, b2, out);
}

// Round 15
// 221.020 us; speedup vs baseline: 1.1167x; 1.1167x over previous
//
#include <hip/hip_runtime.h>
#include <math.h>

#define NN 100000
#define NE 1600000
#define EE 1700000       // NE + NN self loops
#define HD 128
#define NH (NN*HD)

#define BSH 8            // bucket = dst >> 8  (256 nodes per bucket)
#define NBUK 391         // ceil(NN / 256)
#define CAP 6144         // per-bucket staging capacity (mean 4352, sigma ~66)
#define EPB 4096         // edges per partition block
#define P1B ((EE + EPB - 1) / EPB)   // 416
#define GEMMB 1563       // gemm blocks (64 rows each)

typedef _Float16 f16x8 __attribute__((ext_vector_type(8)));
typedef float    f32x4 __attribute__((ext_vector_type(4)));

__device__ __forceinline__ float fast_tanh(float x) {
    float e = __expf(2.f * x);
    return 1.f - 2.f * __builtin_amdgcn_rcpf(e + 1.f);
}

// ====== prep: W (fp32 [k][n]) -> Wt (fp16 [n][k]) for both layers + zero bucketCount ======
__global__ void prep_kernel(const float* __restrict__ W1, const float* __restrict__ W2,
                            _Float16* __restrict__ Wt1, _Float16* __restrict__ Wt2,
                            int* __restrict__ bucketCount) {
    int b = blockIdx.x;
    int t = threadIdx.x;
    if (b < 128) {
        const float* W = (b < 64) ? W1 : W2;
        _Float16* Wt   = (b < 64) ? Wt1 : Wt2;
        int e = (b & 63) * 256 + t;
        int k = e >> 7, n = e & 127;
        Wt[n*HD + k] = (_Float16)W[e];
    } else {
        for (int i = t; i < NBUK; i += 256) bucketCount[i] = 0;
    }
}

// ================= CSR phase 1: bucket partition (standalone, early) =================
__launch_bounds__(256) __global__
void partition_kernel(const int* __restrict__ ei, int* __restrict__ bucketCount,
                      unsigned* __restrict__ stage) {
    __shared__ int hist[NBUK];
    __shared__ int base[NBUK];
    int t = threadIdx.x;
    for (int i = t; i < NBUK; i += 256) hist[i] = 0;
    __syncthreads();
    int e0 = blockIdx.x * EPB;
    int e1 = min(e0 + EPB, EE);
    for (int e = e0 + t; e < e1; e += 256) {
        int d = (e < NE) ? ei[NE + e] : e - NE;
        atomicAdd(&hist[d >> BSH], 1);
    }
    __syncthreads();
    for (int i = t; i < NBUK; i += 256) {
        base[i] = atomicAdd(&bucketCount[i], hist[i]);
        hist[i] = 0;                       // reuse as cursor
    }
    __syncthreads();
    for (int e = e0 + t; e < e1; e += 256) {
        int s, d;
        if (e < NE) { s = ei[e]; d = ei[NE + e]; } else { s = e - NE; d = s; }
        int b = d >> BSH;
        int pos = base[b] + atomicAdd(&hist[b], 1);
        if (pos < CAP)
            stage[(size_t)b * CAP + pos] = (unsigned)s | ((unsigned)(d & 255) << 20);
    }
}

// ====== FUSED: layer-1 GEMM(+scores)  ∥  CSR bucket_build (independent work) ======
__launch_bounds__(256) __global__
void gemm_bb_kernel(const float* __restrict__ A, const _Float16* __restrict__ Wt,
                    _Float16* __restrict__ H, const float* __restrict__ a_src,
                    const float* __restrict__ a_dst, float* __restrict__ s_src,
                    float* __restrict__ s_dst,
                    const unsigned* __restrict__ stage, const int* __restrict__ bucketCount,
                    int* __restrict__ row_ptr, int* __restrict__ csr_src) {
    __shared__ __align__(16) char smem[HD*HD*2 + HD*8];    // 33 KB union
    int bid = blockIdx.x;
    int t = threadIdx.x;

    if (bid < GEMMB) {
        // ---------------- GEMM body ----------------
        _Float16* Wl = (_Float16*)smem;                    // 32 KB, slot-swizzled
        float* asl = (float*)(smem + HD*HD*2);
        float* adl = asl + HD;
        #pragma unroll
        for (int i = 0; i < 8; ++i) {
            int f = t + 256*i;                 // float4 index over 2048
            int n = f >> 4, slot = f & 15;
            int phys = n*16 + (slot ^ (n & 7));
            *(float4*)(Wl + (size_t)phys*8) = ((const float4*)Wt)[f];
        }
        if (t < HD) { asl[t] = a_src[t]; adl[t] = a_dst[t]; }
        __syncthreads();

        int wave = t >> 6, lane = t & 63;
        int row0 = bid*64 + wave*16;
        int h8   = lane >> 4;
        int col  = lane & 15;
        int arow = row0 + col; if (arow >= NN) arow = NN - 1;
        const float* Af = A + (size_t)arow*HD + h8*8;

        f32x4 acc[8];
        #pragma unroll
        for (int i = 0; i < 8; ++i) acc[i] = (f32x4){0.f,0.f,0.f,0.f};

        #pragma unroll
        for (int step = 0; step < 4; ++step) {
            float4 fa = *(const float4*)(Af + step*32);
            float4 fb = *(const float4*)(Af + step*32 + 4);
            f16x8 a = { (_Float16)fa.x, (_Float16)fa.y, (_Float16)fa.z, (_Float16)fa.w,
                        (_Float16)fb.x, (_Float16)fb.y, (_Float16)fb.z, (_Float16)fb.w };
            #pragma unroll
            for (int nt = 0; nt < 8; ++nt) {
                int n = nt*16 + col;
                int slot = step*4 + h8;
                f16x8 bfr = *(const f16x8*)(Wl + (size_t)(n*16 + (slot ^ (n & 7)))*8);
                acc[nt] = __builtin_amdgcn_mfma_f32_16x16x32_f16(a, bfr, acc[nt], 0, 0, 0);
            }
        }

        int orow0 = row0 + h8*4;               // D: col=lane&15, row=(lane>>4)*4+reg
        #pragma unroll
        for (int nt = 0; nt < 8; ++nt) {
            int c = nt*16 + col;
            #pragma unroll
            for (int r = 0; r < 4; ++r) {
                int row = orow0 + r;
                if (row < NN) H[(size_t)row*HD + c] = (_Float16)acc[nt][r];
            }
        }

        float pS[4] = {0.f,0.f,0.f,0.f}, pD[4] = {0.f,0.f,0.f,0.f};
        #pragma unroll
        for (int nt = 0; nt < 8; ++nt) {
            float as_ = asl[nt*16 + col], ad_ = adl[nt*16 + col];
            #pragma unroll
            for (int r = 0; r < 4; ++r) { pS[r] += acc[nt][r]*as_; pD[r] += acc[nt][r]*ad_; }
        }
        #pragma unroll
        for (int off = 1; off < 16; off <<= 1) {
            #pragma unroll
            for (int r = 0; r < 4; ++r) {
                pS[r] += __shfl_xor(pS[r], off);
                pD[r] += __shfl_xor(pD[r], off);
            }
        }
        if (col == 0) {
            #pragma unroll
            for (int r = 0; r < 4; ++r) {
                int row = orow0 + r;
                if (row < NN) { s_src[row] = pS[r]; s_dst[row] = pD[r]; }
            }
        }
    } else {
        // ---------------- bucket_build body ----------------
        int b = bid - GEMMB;
        int* ldeg = (int*)smem;                // 256 ints
        int* loff = ldeg + 256;                // 256 ints
        int* sbase = loff + 256;               // 1 int
        int c = 0;
        if (t < b) c = bucketCount[t];
        if (t + 256 < b) c += bucketCount[t + 256];
        loff[t] = c;
        ldeg[t] = 0;
        __syncthreads();
        for (int off = 128; off >= 1; off >>= 1) {
            if (t < off) loff[t] += loff[t + off];
            __syncthreads();
        }
        if (t == 0) sbase[0] = loff[0];
        __syncthreads();
        int cnt  = bucketCount[b];
        int base = sbase[0];
        const unsigned* sp = stage + (size_t)b * CAP;
        for (int i = t; i < cnt; i += 256) atomicAdd(&ldeg[sp[i] >> 20], 1);
        __syncthreads();
        int v = ldeg[t];
        loff[t] = v;
        __syncthreads();
        for (int off = 1; off < 256; off <<= 1) {
            int tmp = (t >= off) ? loff[t - off] : 0;
            __syncthreads();
            loff[t] += tmp;
            __syncthreads();
        }
        int excl = loff[t] - v;
        int n = (b << BSH) + t;
        if (n < NN) row_ptr[n] = base + excl;
        if (b == NBUK - 1 && t == 0) row_ptr[NN] = EE;
        ldeg[t] = excl;                        // reuse as cursor
        __syncthreads();
        for (int i = t; i < cnt; i += 256) {
            unsigned p = sp[i];
            int lp = atomicAdd(&ldeg[p >> 20], 1);
            csr_src[base + lp] = (int)(p & 0xFFFFFu);
        }
    }
}

// ================= layer-2 GEMM(+scores) =================
__launch_bounds__(256) __global__
void gemm_kernel(const float* __restrict__ A, const _Float16* __restrict__ Wt,
                 _Float16* __restrict__ H, const float* __restrict__ a_src,
                 const float* __restrict__ a_dst, float* __restrict__ s_src,
                 float* __restrict__ s_dst) {
    __shared__ __align__(16) char smem[HD*HD*2 + HD*8];
    int bid = blockIdx.x;
    int t = threadIdx.x;
    _Float16* Wl = (_Float16*)smem;
    float* asl = (float*)(smem + HD*HD*2);
    float* adl = asl + HD;
    #pragma unroll
    for (int i = 0; i < 8; ++i) {
        int f = t + 256*i;
        int n = f >> 4, slot = f & 15;
        int phys = n*16 + (slot ^ (n & 7));
        *(float4*)(Wl + (size_t)phys*8) = ((const float4*)Wt)[f];
    }
    if (t < HD) { asl[t] = a_src[t]; adl[t] = a_dst[t]; }
    __syncthreads();

    int wave = t >> 6, lane = t & 63;
    int row0 = bid*64 + wave*16;
    int h8   = lane >> 4;
    int col  = lane & 15;
    int arow = row0 + col; if (arow >= NN) arow = NN - 1;
    const float* Af = A + (size_t)arow*HD + h8*8;

    f32x4 acc[8];
    #pragma unroll
    for (int i = 0; i < 8; ++i) acc[i] = (f32x4){0.f,0.f,0.f,0.f};

    #pragma unroll
    for (int step = 0; step < 4; ++step) {
        float4 fa = *(const float4*)(Af + step*32);
        float4 fb = *(const float4*)(Af + step*32 + 4);
        f16x8 a = { (_Float16)fa.x, (_Float16)fa.y, (_Float16)fa.z, (_Float16)fa.w,
                    (_Float16)fb.x, (_Float16)fb.y, (_Float16)fb.z, (_Float16)fb.w };
        #pragma unroll
        for (int nt = 0; nt < 8; ++nt) {
            int n = nt*16 + col;
            int slot = step*4 + h8;
            f16x8 bfr = *(const f16x8*)(Wl + (size_t)(n*16 + (slot ^ (n & 7)))*8);
            acc[nt] = __builtin_amdgcn_mfma_f32_16x16x32_f16(a, bfr, acc[nt], 0, 0, 0);
        }
    }

    int orow0 = row0 + h8*4;
    #pragma unroll
    for (int nt = 0; nt < 8; ++nt) {
        int c = nt*16 + col;
        #pragma unroll
        for (int r = 0; r < 4; ++r) {
            int row = orow0 + r;
            if (row < NN) H[(size_t)row*HD + c] = (_Float16)acc[nt][r];
        }
    }

    float pS[4] = {0.f,0.f,0.f,0.f}, pD[4] = {0.f,0.f,0.f,0.f};
    #pragma unroll
    for (int nt = 0; nt < 8; ++nt) {
        float as_ = asl[nt*16 + col], ad_ = adl[nt*16 + col];
        #pragma unroll
        for (int r = 0; r < 4; ++r) { pS[r] += acc[nt][r]*as_; pD[r] += acc[nt][r]*ad_; }
    }
    #pragma unroll
    for (int off = 1; off < 16; off <<= 1) {
        #pragma unroll
        for (int r = 0; r < 4; ++r) {
            pS[r] += __shfl_xor(pS[r], off);
            pD[r] += __shfl_xor(pD[r], off);
        }
    }
    if (col == 0) {
        #pragma unroll
        for (int r = 0; r < 4; ++r) {
            int row = orow0 + r;
            if (row < NN) { s_src[row] = pS[r]; s_dst[row] = pD[r]; }
        }
    }
}

// ================= fused per-node softmax + gather-aggregate (R7/R13-proven body) ============
// 4 nodes/wave (natural order); 4 edges/batch, all 8 gathers issued before compute.
template<int LAYER>
__launch_bounds__(256) __global__
void gat_node_kernel(const int* __restrict__ row_ptr, const int* __restrict__ csr_src,
                     const float* __restrict__ s_src, const float* __restrict__ s_dst,
                     const _Float16* __restrict__ Hh, const float* __restrict__ bias,
                     float* __restrict__ out) {
    int wid = (blockIdx.x * blockDim.x + threadIdx.x) >> 6;
    int lane = threadIdx.x & 63;
    int g = lane >> 4, l16 = lane & 15;
    int n = wid*4 + g;                     // NN divisible by 4: no partial waves
    if (n >= NN) return;
    int r0 = row_ptr[n], r1 = row_ptr[n+1];
    int last = r1 - 1;
    float sdv = s_dst[n];

    float denom = 0.f;
    float acc[8] = {0.f,0.f,0.f,0.f,0.f,0.f,0.f,0.f};

    for (int j = r0; j < r1; j += 4) {
        int jB = j+1 <= last ? j+1 : last;
        int jC = j+2 <= last ? j+2 : last;
        int jD = j+3 <= last ? j+3 : last;
        int sA = csr_src[j];
        int sB = csr_src[jB];
        int sC = csr_src[jC];
        int sD = csr_src[jD];
        // issue all 8 gathers before dependent compute
        f16x8 hA = *(const f16x8*)(Hh + (unsigned)(sA << 7) + l16*8);
        f16x8 hB = *(const f16x8*)(Hh + (unsigned)(sB << 7) + l16*8);
        f16x8 hC = *(const f16x8*)(Hh + (unsigned)(sC << 7) + l16*8);
        f16x8 hD = *(const f16x8*)(Hh + (unsigned)(sD << 7) + l16*8);
        float eA = s_src[sA] + sdv;
        float eB = s_src[sB] + sdv;
        float eC = s_src[sC] + sdv;
        float eD = s_src[sD] + sdv;
        eA = eA > 0.f ? eA : 0.2f*eA;  eB = eB > 0.f ? eB : 0.2f*eB;
        eC = eC > 0.f ? eC : 0.2f*eC;  eD = eD > 0.f ? eD : 0.2f*eD;
        float wA = __expf(fminf(eA, 80.f));
        float wB = (j+1 < r1) ? __expf(fminf(eB, 80.f)) : 0.f;
        float wC = (j+2 < r1) ? __expf(fminf(eC, 80.f)) : 0.f;
        float wD = (j+3 < r1) ? __expf(fminf(eD, 80.f)) : 0.f;
        denom += (wA + wB) + (wC + wD);
        #pragma unroll
        for (int i = 0; i < 8; ++i)
            acc[i] += wA*(float)hA[i] + wB*(float)hB[i] + wC*(float)hC[i] + wD*(float)hD[i];
    }

    float inv = __builtin_amdgcn_rcpf(denom);
    float* op = out + (unsigned)(n << 7) + l16*8;
    float4 b0 = *(const float4*)(bias + l16*8);
    float4 b1 = *(const float4*)(bias + l16*8 + 4);
    float r[8];
    r[0]=acc[0]*inv+b0.x; r[1]=acc[1]*inv+b0.y; r[2]=acc[2]*inv+b0.z; r[3]=acc[3]*inv+b0.w;
    r[4]=acc[4]*inv+b1.x; r[5]=acc[5]*inv+b1.y; r[6]=acc[6]*inv+b1.z; r[7]=acc[7]*inv+b1.w;
    if (LAYER == 1) {
        #pragma unroll
        for (int i = 0; i < 8; ++i) r[i] = fast_tanh(r[i]);
    } else {
        float4 x0 = *(const float4*)op;
        float4 x1 = *(const float4*)(op + 4);
        r[0]=fmaxf(x0.x,r[0]); r[1]=fmaxf(x0.y,r[1]); r[2]=fmaxf(x0.z,r[2]); r[3]=fmaxf(x0.w,r[3]);
        r[4]=fmaxf(x1.x,r[4]); r[5]=fmaxf(x1.y,r[5]); r[6]=fmaxf(x1.z,r[6]); r[7]=fmaxf(x1.w,r[7]);
    }
    *(float4*)op       = make_float4(r[0],r[1],r[2],r[3]);
    *(float4*)(op + 4) = make_float4(r[4],r[5],r[6],r[7]);
}

extern "C" void kernel_launch(void* const* d_in, const int* in_sizes, int n_in,
                              void* d_out, int out_size, void* d_ws, size_t ws_size,
                              hipStream_t stream) {
    const float* x   = (const float*)d_in[0];
    const int*   ei  = (const int*)d_in[1];
    // d_in[2] = edge_weight, unused by GATConv(edge_dim=None)
    const float* W1  = (const float*)d_in[3];
    const float* as1 = (const float*)d_in[4];
    const float* ad1 = (const float*)d_in[5];
    const float* b1  = (const float*)d_in[6];
    const float* W2  = (const float*)d_in[7];
    const float* as2 = (const float*)d_in[8];
    const float* ad2 = (const float*)d_in[9];
    const float* b2  = (const float*)d_in[10];
    float* out = (float*)d_out;

    char* wsb = (char*)d_ws;
    _Float16* h   = (_Float16*)wsb;                  // NH halves (25.6 MB)
    _Float16* Wt1 = h + NH;                          // 16384 halves
    _Float16* Wt2 = Wt1 + HD*HD;                     // 16384 halves
    float* ssrc   = (float*)(Wt2 + HD*HD);           // NN
    float* sdst   = ssrc + NN;                       // NN
    int* row_ptr  = (int*)(sdst + NN);               // NN+2
    int* csr_src  = row_ptr + NN + 2;                // EE
    int* bucketCount = csr_src + EE;                 // NBUK (zeroed by prep each launch)
    unsigned* stage  = (unsigned*)(bucketCount + NBUK + 1);  // NBUK*CAP (9.6 MB)

    dim3 B(256);
    int node_blocks = NN / 16;                       // 6250 (4 nodes/wave, 4 waves/block)

    // ===== prep: Wt transposes (both layers) + zero bucket counters =====
    prep_kernel<<<129, B, 0, stream>>>(W1, W2, Wt1, Wt2, bucketCount);

    // ===== CSR phase 1 (early, standalone; only needs ei) =====
    partition_kernel<<<P1B, B, 0, stream>>>(ei, bucketCount, stage);

    // ===== layer-1 GEMM ∥ CSR bucket_build (independent work, one dispatch) =====
    gemm_bb_kernel<<<GEMMB + NBUK, B, 0, stream>>>(x, Wt1, h, as1, ad1, ssrc, sdst,
                                                   stage, bucketCount, row_ptr, csr_src);

    // ===== layer 1 aggregate =====
    gat_node_kernel<1><<<node_blocks, B, 0, stream>>>(row_ptr, csr_src, ssrc, sdst, h, b1, out);

    // ===== layer 2 (x1 fp32 lives in d_out; max fused into epilogue) =====
    gemm_kernel<<<GEMMB, B, 0, stream>>>(out, Wt2, h, as2, ad2, ssrc, sdst);
    gat_node_kernel<2><<<node_blocks, B, 0, stream>>>(row_ptr, csr_src, ssrc, sdst, h, b2, out);
}